// Round 5
// baseline (643.330 us; speedup 1.0000x reference)
//
#include <hip/hip_runtime.h>
#include <math.h>

// ---------------------------------------------------------------------------
// Round 5: 128-pt tile, 2 blocks/CU. 32x32x16 MFMA, 4 waves x 64ch, nt=4.
// Halves (vs r4): barriers/point, A-load instrs/point, L2 weight traffic.
// A-pack: [ch][Kpad] (r2-proven) -> kk A-loads are immediates off 2 base ptrs.
// B-reads: one LDS addr/kk + nt*16KB 16-bit immediates.
// LDS: act 128x256 bf16 (64KB) + emb 128x64 (16KB) = 80KB, XOR-16B swizzle
// (r4-proven). Numerics: bf16 W+act, fp32 acc -> absmax 3.9e-3 (proven).
// ---------------------------------------------------------------------------

typedef __attribute__((ext_vector_type(8))) short short8;
typedef __attribute__((ext_vector_type(4))) float f32x4;
typedef __attribute__((ext_vector_type(16))) float f32x16;

struct WPtrs { const float* w[8]; };
struct BPtrs { const float* b[8]; };

#define INV2PI 0.15915494309189533577f

// element offsets, layout per layer [ch 0..255][Kpad]:
// Kpad: L0=64, L1-4=256, L5=320, L6-7=256 ; W8 as [j16][k256]
#define PK_L0 0
#define PK_L1 16384
#define PK_L2 81920
#define PK_L3 147456
#define PK_L4 212992
#define PK_L5 278528
#define PK_L6 360448
#define PK_L7 425984
#define PK_W8 491520
#define PK_TOTAL 495616

__device__ __forceinline__ unsigned short f2bf(float v) {
  unsigned u = __float_as_uint(v);
  u = u + 0x7fffu + ((u >> 16) & 1u);
  return (unsigned short)(u >> 16);
}
__device__ __forceinline__ float bf_lo(unsigned u) { return __uint_as_float(u << 16); }
__device__ __forceinline__ float bf_hi(unsigned u) { return __uint_as_float(u & 0xffff0000u); }

__device__ __forceinline__ unsigned cvtpk(float a, float b) {
#if __has_builtin(__builtin_amdgcn_cvt_pk_bf16_f32)
  typedef __attribute__((ext_vector_type(2))) __bf16 bf16x2_t;
  bf16x2_t r = __builtin_amdgcn_cvt_pk_bf16_f32(a, b);
  return __builtin_bit_cast(unsigned, r);
#else
  unsigned ua = __float_as_uint(a);
  ua += 0x7fffu + ((ua >> 16) & 1u);
  unsigned ub = __float_as_uint(b);
  ub += 0x7fffu + ((ub >> 16) & 1u);
#if __has_builtin(__builtin_amdgcn_perm)
  return __builtin_amdgcn_perm(ub, ua, 0x07060302u);
#else
  return (ua >> 16) | (ub & 0xffff0000u);
#endif
#endif
}

__device__ __forceinline__ float fractf_(float x) {
#if __has_builtin(__builtin_amdgcn_fract_f32)
  return __builtin_amdgcn_fract_f32(x);
#else
  return x - floorf(x);
#endif
}
__device__ __forceinline__ float sin_rev(float rev) {
#if __has_builtin(__builtin_amdgcn_sinf)
  return __builtin_amdgcn_sinf(rev);
#else
  return __sinf(rev * 6.283185307179586f);
#endif
}

__device__ __forceinline__ float embval(int f, float c0, float c1, float c2,
                                        float x0, float x1, float x2) {
  if (f >= 63) return 0.0f;
  int d = (f >= 21 ? 1 : 0) + (f >= 42 ? 1 : 0);
  int r = f - d * 21;
  float c = (d == 0) ? c0 : (d == 1 ? c1 : c2);
  float x = (d == 0) ? x0 : (d == 1 ? x1 : x2);
  bool isc = r > 10;
  int e = isc ? (r - 11) : (r - 1);
  float rev = fractf_(ldexpf(x, e) + (isc ? 0.25f : 0.0f));
  float s = sin_rev(rev);
  return (r == 0) ? c : s;
}

__device__ __forceinline__ f32x16 mfma32(short8 a, short8 b, f32x16 c) {
  return __builtin_amdgcn_mfma_f32_32x32x16_bf16(a, b, c, 0, 0, 0);
}
__device__ __forceinline__ f32x4 mfma16(short8 a, short8 b, f32x4 c) {
  return __builtin_amdgcn_mfma_f32_16x16x32_bf16(a, b, c, 0, 0, 0);
}

// ---------------------------------------------------------------------------
// Prologue (r2-proven): pack W^T as [ch][Kpad] bf16 per layer; W8 [j16][k256].
// ---------------------------------------------------------------------------
__global__ void pack_weights(WPtrs W, const float* __restrict__ w8,
                             unsigned short* __restrict__ out) {
  int idx = blockIdx.x * 256 + threadIdx.x;
  if (idx >= PK_TOTAL) return;
  float v;
  if (idx >= PK_W8) {
    int t = idx - PK_W8;
    int j = t >> 8, k = t & 255;
    v = (j < 4) ? w8[k * 4 + j] : 0.0f;
  } else {
    int l, base, kpad, realk;
    if      (idx < PK_L1) { l = 0; base = PK_L0; kpad = 64;  realk = 63;  }
    else if (idx < PK_L2) { l = 1; base = PK_L1; kpad = 256; realk = 256; }
    else if (idx < PK_L3) { l = 2; base = PK_L2; kpad = 256; realk = 256; }
    else if (idx < PK_L4) { l = 3; base = PK_L3; kpad = 256; realk = 256; }
    else if (idx < PK_L5) { l = 4; base = PK_L4; kpad = 256; realk = 256; }
    else if (idx < PK_L6) { l = 5; base = PK_L5; kpad = 320; realk = 319; }
    else if (idx < PK_L7) { l = 6; base = PK_L6; kpad = 256; realk = 256; }
    else                  { l = 7; base = PK_L7; kpad = 256; realk = 256; }
    int t = idx - base;
    int ch = t / kpad, k = t - ch * kpad;
    v = (k < realk) ? W.w[l][k * 256 + ch] : 0.0f;
  }
  out[idx] = f2bf(v);
}

// ---------------------------------------------------------------------------
// One layer via 32x32x16, nt=4 (128 pts). A: [ch][KPAD] global, immediate kk
// offsets off 2 base pointers. B: LDS rows PAB bytes, XOR-16B swizzle, one
// address + nt*32*PAB immediates. KKB extra kk from emb. RB: barrier before
// writeback (src aliases dst).
// ---------------------------------------------------------------------------
template <int KKA, int KPAD, int PAB, int KKB, bool RB>
__device__ __forceinline__ void do_layer32(
    const unsigned short* srcA, const unsigned short* srcB,
    const unsigned short* __restrict__ wblk,
    const float* __restrict__ bias,
    unsigned short* dst, int w, int n, int h, unsigned swz) {
  f32x16 acc[2][4];
#pragma unroll
  for (int mt = 0; mt < 2; ++mt)
#pragma unroll
    for (int q = 0; q < 4; ++q) {
      f32x4 bq = *reinterpret_cast<const f32x4*>(bias + w * 64 + mt * 32 + q * 8 + h * 4);
#pragma unroll
      for (int r = 0; r < 4; ++r)
#pragma unroll
        for (int nt = 0; nt < 4; ++nt)
          acc[mt][nt][q * 4 + r] = bq[r];
    }

  const unsigned short* ab0 = wblk + (unsigned)((w * 64 + n) * KPAD + h * 8);
  const unsigned short* ab1 = ab0 + 32 * KPAD;
  const char* rbase = (const char*)srcA + (unsigned)(n * PAB);

#pragma unroll 4
  for (int kk = 0; kk < KKA; ++kk) {
    short8 a0 = *reinterpret_cast<const short8*>(ab0 + kk * 16);
    short8 a1 = *reinterpret_cast<const short8*>(ab1 + kk * 16);
    unsigned off = ((unsigned)(kk * 32 + h * 16)) ^ swz;
    short8 b[4];
#pragma unroll
    for (int nt = 0; nt < 4; ++nt)
      b[nt] = *reinterpret_cast<const short8*>(rbase + nt * 32 * PAB + off);
#pragma unroll
    for (int nt = 0; nt < 4; ++nt) {
      acc[0][nt] = mfma32(a0, b[nt], acc[0][nt]);
      acc[1][nt] = mfma32(a1, b[nt], acc[1][nt]);
    }
  }
  if (KKB > 0) {
    const char* rbB = (const char*)srcB + (unsigned)(n * 128);
#pragma unroll
    for (int kl = 0; kl < KKB; ++kl) {
      short8 a0 = *reinterpret_cast<const short8*>(ab0 + (KKA + kl) * 16);
      short8 a1 = *reinterpret_cast<const short8*>(ab1 + (KKA + kl) * 16);
      unsigned off = ((unsigned)(kl * 32 + h * 16)) ^ swz;
      short8 b[4];
#pragma unroll
      for (int nt = 0; nt < 4; ++nt)
        b[nt] = *reinterpret_cast<const short8*>(rbB + nt * 32 * 128 + off);
#pragma unroll
      for (int nt = 0; nt < 4; ++nt) {
        acc[0][nt] = mfma32(a0, b[nt], acc[0][nt]);
        acc[1][nt] = mfma32(a1, b[nt], acc[1][nt]);
      }
    }
  }

  if (RB) __syncthreads();   // all waves done reading src (aliases dst)
#pragma unroll
  for (int nt = 0; nt < 4; ++nt) {
    char* rowp = (char*)dst + (unsigned)((nt * 32 + n) * 512);
#pragma unroll
    for (int mt = 0; mt < 2; ++mt)
#pragma unroll
      for (int q = 0; q < 4; ++q) {
        float x0 = fmaxf(acc[mt][nt][q * 4 + 0], 0.0f);
        float x1 = fmaxf(acc[mt][nt][q * 4 + 1], 0.0f);
        float x2 = fmaxf(acc[mt][nt][q * 4 + 2], 0.0f);
        float x3 = fmaxf(acc[mt][nt][q * 4 + 3], 0.0f);
        uint2 pr;
        pr.x = cvtpk(x0, x1);
        pr.y = cvtpk(x2, x3);
        unsigned off = ((unsigned)(w * 128 + mt * 64 + q * 16 + h * 8)) ^ swz;
        *reinterpret_cast<uint2*>(rowp + off) = pr;
      }
  }
  __syncthreads();           // writes visible
}

__launch_bounds__(256, 2)
__global__ void mlp_mfma(const float* __restrict__ pts, long N,
                         BPtrs B, const float* __restrict__ b8,
                         const unsigned short* __restrict__ wpk,
                         float* __restrict__ out) {
  __shared__ unsigned short act[128 * 256];  // 64 KB, [pt][ch] swizzled
  __shared__ unsigned short emb[128 * 64];   // 16 KB, [pt][f]  swizzled
  const int tid = threadIdx.x;
  const int w = tid >> 6, lane = tid & 63;
  const int n = lane & 31, h = lane >> 5;
  const unsigned swz = (unsigned)((n & 7) << 4);   // == (pt&7)<<4 for B-rows
  const long pbase = (long)blockIdx.x * 128;

  // ---- embedding: 2 passes; thread t -> point (t>>2)+64*p2, 16 features ---
#pragma unroll
  for (int p2 = 0; p2 < 2; ++p2) {
    const int pt = (tid >> 2) + (p2 << 6), fg = tid & 3;
    const long pg = pbase + pt;
    float c0 = 0.f, c1 = 0.f, c2 = 0.f;
    if (pg < N) {
      const float* pp = pts + pg * 3;
      c0 = pp[0]; c1 = pp[1]; c2 = pp[2];
    }
    float x0 = c0 * INV2PI, x1 = c1 * INV2PI, x2 = c2 * INV2PI;
    unsigned pk[8];
#pragma unroll
    for (int i = 0; i < 16; i += 2) {
      int f0 = fg * 16 + i;
      float v0 = embval(f0,     c0, c1, c2, x0, x1, x2);
      float v1 = embval(f0 + 1, c0, c1, c2, x0, x1, x2);
      pk[i >> 1] = cvtpk(v0, v1);
    }
    const unsigned sw = (unsigned)((pt & 7) << 4);
    char* rowp = (char*)emb + (unsigned)(pt * 128);
    *reinterpret_cast<uint4*>(rowp + (((unsigned)(fg * 32)) ^ sw)) =
        uint4{pk[0], pk[1], pk[2], pk[3]};
    *reinterpret_cast<uint4*>(rowp + (((unsigned)(fg * 32 + 16)) ^ sw)) =
        uint4{pk[4], pk[5], pk[6], pk[7]};
  }
  __syncthreads();

  do_layer32<4,  64,  128, 0, false>(emb, nullptr, wpk + PK_L0, B.b[0], act, w, n, h, swz);
  do_layer32<16, 256, 512, 0, true >(act, nullptr, wpk + PK_L1, B.b[1], act, w, n, h, swz);
  do_layer32<16, 256, 512, 0, true >(act, nullptr, wpk + PK_L2, B.b[2], act, w, n, h, swz);
  do_layer32<16, 256, 512, 0, true >(act, nullptr, wpk + PK_L3, B.b[3], act, w, n, h, swz);
  do_layer32<16, 256, 512, 0, true >(act, nullptr, wpk + PK_L4, B.b[4], act, w, n, h, swz);
  do_layer32<16, 320, 512, 4, true >(act, emb,     wpk + PK_L5, B.b[5], act, w, n, h, swz);
  do_layer32<16, 256, 512, 0, true >(act, nullptr, wpk + PK_L6, B.b[6], act, w, n, h, swz);
  do_layer32<16, 256, 512, 0, true >(act, nullptr, wpk + PK_L7, B.b[7], act, w, n, h, swz);

  // ---- final 256->4 via 16x16x32: wave w -> pts [32w, 32w+32) -------------
  {
    const int l16 = lane & 15, quad = lane >> 4;
    const unsigned short* w8b = wpk + PK_W8 + (unsigned)(l16 * 256 + quad * 8);
    const f32x4 bb = *reinterpret_cast<const f32x4*>(b8);
#pragma unroll
    for (int it = 0; it < 2; ++it) {
      const int pt = w * 32 + it * 16 + l16;
      const char* ba = (const char*)act + (unsigned)(pt * 512);
      f32x4 a4 = {0.f, 0.f, 0.f, 0.f};
#pragma unroll
      for (int kk = 0; kk < 8; ++kk) {
        short8 a = *reinterpret_cast<const short8*>(w8b + kk * 32);
        unsigned off = ((unsigned)(kk * 64 + quad * 16)) ^ ((unsigned)((l16 & 7) << 4));
        short8 b = *reinterpret_cast<const short8*>(ba + off);
        a4 = mfma16(a, b, a4);
      }
      if (quad == 0) {
        long pg = pbase + pt;
        f32x4 v = a4 + bb;
        if (pg < N) *reinterpret_cast<f32x4*>(out + pg * 4) = v;
      }
    }
  }
}

// ---------------------------------------------------------------------------
// Fallback (ws too small): round-1 VALU kernel, fp32 weights, proven correct.
// ---------------------------------------------------------------------------
__device__ __forceinline__ unsigned pk2s(float a, float b) {
  return (unsigned)f2bf(a) | ((unsigned)f2bf(b) << 16);
}
__device__ __forceinline__ void fb_seg(const unsigned short* src, int kRows,
                                       const float* __restrict__ wr,
                                       int lane, int ps, float acc[4][16]) {
#pragma unroll 4
  for (int k = 0; k < kRows; ++k) {
    const float* p = wr + k * 256 + lane;
    float w0 = p[0], w1 = p[64], w2 = p[128], w3 = p[192];
    const uint4* xr = reinterpret_cast<const uint4*>(src + ((k << 6) + ps));
    uint4 q0 = xr[0], q1 = xr[1];
    float x[16];
    x[0] = bf_lo(q0.x);  x[1] = bf_hi(q0.x);  x[2] = bf_lo(q0.y);  x[3] = bf_hi(q0.y);
    x[4] = bf_lo(q0.z);  x[5] = bf_hi(q0.z);  x[6] = bf_lo(q0.w);  x[7] = bf_hi(q0.w);
    x[8] = bf_lo(q1.x);  x[9] = bf_hi(q1.x);  x[10] = bf_lo(q1.y); x[11] = bf_hi(q1.y);
    x[12] = bf_lo(q1.z); x[13] = bf_hi(q1.z); x[14] = bf_lo(q1.w); x[15] = bf_hi(q1.w);
#pragma unroll
    for (int pp = 0; pp < 16; ++pp) {
      acc[0][pp] = fmaf(w0, x[pp], acc[0][pp]);
      acc[1][pp] = fmaf(w1, x[pp], acc[1][pp]);
      acc[2][pp] = fmaf(w2, x[pp], acc[2][pp]);
      acc[3][pp] = fmaf(w3, x[pp], acc[3][pp]);
    }
  }
}
__device__ __forceinline__ void fb_layer(const unsigned short* srcA, int kA,
                                         const unsigned short* srcB, int kB,
                                         const float* wrA, const float* wrB,
                                         const float* bias,
                                         unsigned short* dst, int lane, int ps) {
  float acc[4][16];
#pragma unroll
  for (int jt = 0; jt < 4; ++jt) {
    float bb = bias[lane + (jt << 6)];
#pragma unroll
    for (int pp = 0; pp < 16; ++pp) acc[jt][pp] = bb;
  }
  fb_seg(srcA, kA, wrA, lane, ps, acc);
  if (srcB) fb_seg(srcB, kB, wrB, lane, ps, acc);
#pragma unroll
  for (int jt = 0; jt < 4; ++jt) {
    unsigned short* dr = dst + (((lane + (jt << 6)) << 6) + ps);
    float r[16];
#pragma unroll
    for (int pp = 0; pp < 16; ++pp) r[pp] = fmaxf(acc[jt][pp], 0.0f);
    uint4 a, b;
    a.x = pk2s(r[0], r[1]);   a.y = pk2s(r[2], r[3]);
    a.z = pk2s(r[4], r[5]);   a.w = pk2s(r[6], r[7]);
    b.x = pk2s(r[8], r[9]);   b.y = pk2s(r[10], r[11]);
    b.z = pk2s(r[12], r[13]); b.w = pk2s(r[14], r[15]);
    reinterpret_cast<uint4*>(dr)[0] = a;
    reinterpret_cast<uint4*>(dr)[1] = b;
  }
}
__launch_bounds__(256, 2)
__global__ void mlp_fallback(const float* __restrict__ pts, int N,
                             WPtrs W, BPtrs B,
                             const float* __restrict__ w8,
                             const float* __restrict__ b8,
                             float* __restrict__ out) {
  __shared__ unsigned short act[256 * 64];
  __shared__ unsigned short emb[64 * 64];
  const int lane = threadIdx.x & 63;
  const int ps = (threadIdx.x >> 6) << 4;
  const long pbase = (long)blockIdx.x * 64 + ps;
#pragma unroll
  for (int i = 0; i < 16; ++i) {
    int idx = (i << 6) + lane;
    int f = idx >> 4, pp = idx & 15;
    float v = 0.0f;
    if (f < 63) {
      float c = (pbase + pp < N) ? pts[(pbase + pp) * 3 + (f / 21)] : 0.0f;
      float x = c * INV2PI;
      v = embval(f, c, c, c, x, x, x);
    }
    emb[(f << 6) + ps + pp] = f2bf(v);
  }
  fb_layer(emb, 63, nullptr, 0, W.w[0], nullptr, B.b[0], act, lane, ps);
#pragma unroll 1
  for (int l = 1; l <= 4; ++l)
    fb_layer(act, 256, nullptr, 0, W.w[l], nullptr, B.b[l], act, lane, ps);
  fb_layer(act, 256, emb, 63, W.w[5], W.w[5] + 256 * 256, B.b[5], act, lane, ps);
#pragma unroll 1
  for (int l = 6; l <= 7; ++l)
    fb_layer(act, 256, nullptr, 0, W.w[l], nullptr, B.b[l], act, lane, ps);
  {
    const int pp = lane & 15, cc = lane >> 4;
    float a = b8[cc];
#pragma unroll 4
    for (int k = 0; k < 256; ++k)
      a = fmaf(bf_lo((unsigned)act[(k << 6) + ps + pp]), w8[(k << 2) + cc], a);
    if (pbase + pp < N) out[(pbase + pp) * 4 + cc] = a;
  }
}

extern "C" void kernel_launch(void* const* d_in, const int* in_sizes, int n_in,
                              void* d_out, int out_size, void* d_ws, size_t ws_size,
                              hipStream_t stream) {
  const float* pts = (const float*)d_in[0];
  WPtrs W; BPtrs B;
  for (int i = 0; i < 8; ++i) {
    W.w[i] = (const float*)d_in[1 + 2 * i];
    B.b[i] = (const float*)d_in[2 + 2 * i];
  }
  const float* w8 = (const float*)d_in[17];
  const float* b8 = (const float*)d_in[18];
  float* out = (float*)d_out;
  const long N = in_sizes[0] / 3;

  const size_t need = (size_t)PK_TOTAL * sizeof(unsigned short);
  if (ws_size >= need) {
    unsigned short* wpk = (unsigned short*)d_ws;
    pack_weights<<<1936, 256, 0, stream>>>(W, w8, wpk);
    mlp_mfma<<<(int)((N + 127) / 128), 256, 0, stream>>>(pts, N, B, b8, wpk, out);
  } else {
    mlp_fallback<<<(int)((N + 63) / 64), 256, 0, stream>>>(pts, (int)N, W, B, w8, b8, out);
  }
}